// Round 12
// baseline (489.408 us; speedup 1.0000x reference)
//
#include <hip/hip_runtime.h>
#include <hip/hip_bf16.h>

// VectorQuantizer B=32768, K=4096, D=512, fp32 in/out.
// Out concat (f32): quantized_st[B*512] | indices[B] | loss | perplexity | encodings[B*4096].
// R12: 256x256-tile GEMM screen (8 waves, 2Mx4N), 128KB dynamic LDS, BK=64 dbuf,
// 1 barrier/kt. Halves staged L2 traffic vs 128^2 (2GB->1GB). shfl_xor top-2
// epilogue (no LDS merge). Partials layout/reduce byte-identical to R11
// (numpy-fp32 rescore verbatim, validated R5-R11). XCD-bijective swizzle.

typedef __attribute__((ext_vector_type(8))) short bf16x8;
typedef __attribute__((ext_vector_type(4))) float f32x4;

#define BB 32768
#define KK 4096
#define DD 512

#define IDX_OFF  (BB*DD)
#define LOSS_OFF (IDX_OFF + BB)
#define PERP_OFF (LOSS_OFF + 1)
#define ENC_OFF  (PERP_OFF + 1)

// ws byte offsets
#define WSB_XSQ  0
#define WSB_ESQ  131072
#define WSB_IDX  147456
#define WSB_HIST 278528
#define WSB_LOSS 294912
#define WSB_EBF2 294928          // 4 MB: E bf16, packed per (cb2,kt) 32KB chunk
#define WSB_XBF  4489232         // 32 MB: X bf16, packed per (rb2,kt) 32KB chunk
#define WSB_PART 38043664        // 16 MB: uint2 partials [64][32768]

#define MARG 2.5e-4f
#define NCAND 16

static __device__ __forceinline__ unsigned short f2bf(float f) {
    __hip_bfloat16 h = __float2bfloat16(f);
    return *reinterpret_cast<unsigned short*>(&h);
}

static __device__ __forceinline__ unsigned int packscore(float s, int col) {
    unsigned int u = __float_as_uint(s);
    u ^= (u & 0x80000000u) ? 0xFFFFFFFFu : 0x80000000u;
    return (u & 0xFFFFF000u) | (unsigned int)col;
}
static __device__ __forceinline__ float unpackscore(unsigned int p) {
    unsigned int u = p & 0xFFFFF000u;
    u = (u & 0x80000000u) ? (u ^ 0x80000000u) : ~u;
    return __uint_as_float(u);
}

static __device__ __forceinline__ void gll16(const void* g, void* l) {
    __builtin_amdgcn_global_load_lds(
        (const __attribute__((address_space(1))) unsigned int*)g,
        (__attribute__((address_space(3))) unsigned int*)l, 16, 0, 0);
}

__global__ __launch_bounds__(256) void init_kernel(int* __restrict__ hist,
                                                   double* __restrict__ loss_acc) {
    int i = blockIdx.x * 256 + threadIdx.x;
    if (i < KK) hist[i] = 0;
    if (i == 0) *loss_acc = 0.0;
}

// numpy-emulated row sum-of-squares (pairwise-128 + AVX512 lane fold) — validated R5-R11
__global__ __launch_bounds__(256) void npsum_kernel(const float* __restrict__ X,
                                                    const float* __restrict__ E,
                                                    float* __restrict__ xsq,
                                                    float* __restrict__ esq) {
    __shared__ float sq[4][512];
    __shared__ float ub[4][64];
    __shared__ float bb[4][4];
    int w = threadIdx.x >> 6, lane = threadIdx.x & 63;
    int row = blockIdx.x * 4 + w;
    const float* src; float* dst;
    if (row < BB) { src = X + (size_t)row * DD;        dst = xsq + row; }
    else          { src = E + (size_t)(row - BB) * DD; dst = esq + (row - BB); }
    #pragma unroll
    for (int m = 0; m < 8; ++m) {
        float v = src[m * 64 + lane];
        sq[w][m * 64 + lane] = __fmul_rn(v, v);
    }
    __syncthreads();
    {
        int b = lane >> 4, l = lane & 15;
        const float* s = &sq[w][b * 128];
        float t = __fadd_rn(
            __fadd_rn(__fadd_rn(s[l], s[16 + l]), __fadd_rn(s[32 + l], s[48 + l])),
            __fadd_rn(__fadd_rn(s[64 + l], s[80 + l]), __fadd_rn(s[96 + l], s[112 + l])));
        ub[w][lane] = t;
    }
    __syncthreads();
    if (lane < 4) {
        const float* u = &ub[w][lane * 16];
        float T3[8], T6[4];
        #pragma unroll
        for (int i = 0; i < 8; ++i) T3[i] = __fadd_rn(u[i], u[i + 8]);
        #pragma unroll
        for (int i = 0; i < 4; ++i) T6[i] = __fadd_rn(T3[i], T3[i + 4]);
        bb[w][lane] = __fadd_rn(__fadd_rn(T6[0], T6[2]), __fadd_rn(T6[1], T6[3]));
    }
    __syncthreads();
    if (lane == 0)
        *dst = __fadd_rn(__fadd_rn(bb[w][0], bb[w][1]), __fadd_rn(bb[w][2], bb[w][3]));
}

// fp32 row-major [rows][512] -> bf16 packed 32KB chunks (256 rows x 64 k).
// t: chunk=t>>11 (rb2*8+kt), u=t&2047 = (rf*2+ks)*64+lane;
// holds src[rb2*256+rf*16+(lane&15)][kt*64+ks*32+(lane>>4)*8 .. +7]
__global__ __launch_bounds__(256) void pack_kernel(const float* __restrict__ src,
                                                   unsigned short* __restrict__ dst) {
    int t = blockIdx.x * 256 + threadIdx.x;
    int chunk = t >> 11, u = t & 2047;
    int rb2 = chunk >> 3, kt = chunk & 7;
    int rf = u >> 7, ks = (u >> 6) & 1, lane = u & 63;
    int row = rb2 * 256 + rf * 16 + (lane & 15);
    int k   = kt * 64 + ks * 32 + (lane >> 4) * 8;
    const float4* s = (const float4*)(src + (size_t)row * DD + k);
    float4 a = s[0], b = s[1];
    union { bf16x8 v; unsigned short us[8]; } pk;
    pk.us[0] = f2bf(a.x); pk.us[1] = f2bf(a.y); pk.us[2] = f2bf(a.z); pk.us[3] = f2bf(a.w);
    pk.us[4] = f2bf(b.x); pk.us[5] = f2bf(b.y); pk.us[6] = f2bf(b.z); pk.us[7] = f2bf(b.w);
    *(bf16x8*)(dst + (size_t)t * 8) = pk.v;
}

// GEMM screen: grid 2048 = 128 rb2 x 16 cb2 (XCD-swizzled), 512 thr (8 waves 2Mx4N).
// Dynamic LDS 128KB: [0,32K)A0 [32K,64K)A1 [64K,96K)B0 [96K,128K)B1.
__global__ __launch_bounds__(512, 2) void gemm_screen(
    const unsigned short* __restrict__ Xbf, const unsigned short* __restrict__ Ebf2,
    const float* __restrict__ esqw, uint2* __restrict__ partials)
{
    extern __shared__ __align__(16) char pool[];

    const int tid = threadIdx.x;
    const int w = tid >> 6, lane = tid & 63;
    const int c = lane & 15, g = lane >> 4;
    const int bid = blockIdx.x;
    const int orig = (bid & 7) * 256 + (bid >> 3);   // bijective: 2048 % 8 == 0
    const int rb2 = orig >> 4, cb2 = orig & 15;
    const int row0 = rb2 * 256, col0 = cb2 * 256;
    const int mw = w >> 2, nw = w & 3;               // 2M x 4N

    const char* Xc = (const char*)Xbf  + (size_t)rb2 * 8 * 32768;
    const char* Ec = (const char*)Ebf2 + (size_t)cb2 * 8 * 32768;

    f32x4 acc[8][4];
    #pragma unroll
    for (int i = 0; i < 8; ++i)
        #pragma unroll
        for (int j = 0; j < 4; ++j) acc[i][j] = (f32x4){0.f, 0.f, 0.f, 0.f};

    // stage one 32KB chunk: 4 gll16 calls x 512 thr x 16B
    #define STAGE(srcc_, kt_, dstoff_) { \
        const char* s_ = (srcc_) + (size_t)(kt_) * 32768 + (size_t)tid * 16; \
        char* d_ = pool + (dstoff_) + w * 1024; \
        gll16(s_,          d_); \
        gll16(s_ + 8192,   d_ + 8192); \
        gll16(s_ + 16384,  d_ + 16384); \
        gll16(s_ + 24576,  d_ + 24576); }

    STAGE(Xc, 0, 0); STAGE(Ec, 0, 65536);
    __syncthreads();
    int buf = 0;
    for (int kt = 0; kt < 8; ++kt) {
        if (kt < 7) {
            STAGE(Xc, kt + 1, (buf ^ 1) * 32768);
            STAGE(Ec, kt + 1, 65536 + (buf ^ 1) * 32768);
        }
        const char* Ap = pool + buf * 32768;
        const char* Bp = pool + 65536 + buf * 32768;
        #pragma unroll
        for (int ks = 0; ks < 2; ++ks) {
            bf16x8 bfr[4];
            #pragma unroll
            for (int j = 0; j < 4; ++j)
                bfr[j] = *(const bf16x8*)(Bp + ((((nw * 4 + j) * 2 + ks) * 64) + lane) * 16);
            #pragma unroll
            for (int i = 0; i < 8; ++i) {
                bf16x8 af = *(const bf16x8*)(Ap + ((((mw * 8 + i) * 2 + ks) * 64) + lane) * 16);
                #pragma unroll
                for (int j = 0; j < 4; ++j)
                    acc[i][j] = __builtin_amdgcn_mfma_f32_16x16x32_bf16(af, bfr[j], acc[i][j], 0, 0, 0);
            }
        }
        __syncthreads();
        buf ^= 1;
    }

    // epilogue: per-(mf,r) top2 over 4 nf in-reg, then shfl_xor merge across 16
    // c-lanes (sorted-pair merge), lane c==0 writes partials[(cb2*4+nw)][row].
    float es[4];
    #pragma unroll
    for (int nf = 0; nf < 4; ++nf) es[nf] = esqw[col0 + nw * 64 + nf * 16 + c];
    #pragma unroll
    for (int mf = 0; mf < 8; ++mf) {
        #pragma unroll
        for (int r = 0; r < 4; ++r) {
            unsigned int q1 = 0xFFFFFFFFu, q2 = 0xFFFFFFFFu;
            #pragma unroll
            for (int nf = 0; nf < 4; ++nf) {
                int col = col0 + nw * 64 + nf * 16 + c;
                float s = fmaf(-2.0f, acc[mf][nf][r], es[nf]);
                unsigned int q = packscore(s, col);
                if (q < q1) { q2 = q1; q1 = q; } else if (q < q2) q2 = q;
            }
            #pragma unroll
            for (int off = 1; off < 16; off <<= 1) {
                unsigned int o1 = (unsigned int)__shfl_xor((int)q1, off, 64);
                unsigned int o2 = (unsigned int)__shfl_xor((int)q2, off, 64);
                unsigned int n1 = min(q1, o1);
                unsigned int n2 = min(max(q1, o1), min(q2, o2));
                q1 = n1; q2 = n2;
            }
            if (c == 0) {
                int row = row0 + mw * 128 + mf * 16 + g * 4 + r;
                partials[(size_t)(cb2 * 4 + nw) * BB + row] = make_uint2(q1, q2);
            }
        }
    }
    #undef STAGE
}

// merge partials -> candidates -> numpy-fp32 rescore -> idx/hist/loss (verbatim R11)
__global__ __launch_bounds__(256) void reduce_kernel(
    const float* __restrict__ X, const float* __restrict__ E,
    const float* __restrict__ xsqw, const float* __restrict__ esqw,
    const uint2* __restrict__ partials, int* __restrict__ idxbuf,
    int* __restrict__ hist, double* __restrict__ loss_acc,
    float* __restrict__ out)
{
    __shared__ double lred[256];
    const int row = blockIdx.x * 256 + threadIdx.x;
    unsigned int m = 0xFFFFFFFFu;
    for (int e = 0; e < 64; ++e) m = min(m, partials[(size_t)e * BB + row].x);
    float lim = unpackscore(m) + MARG;
    int cand[NCAND]; int nc = 0;
    for (int e = 0; e < 64; ++e) {
        uint2 p = partials[(size_t)e * BB + row];
        if (unpackscore(p.x) <= lim && nc < NCAND) cand[nc++] = (int)(p.x & 0xFFFu);
        if (unpackscore(p.y) <= lim && nc < NCAND) cand[nc++] = (int)(p.y & 0xFFFu);
    }
    const float* xr = X + (size_t)row * DD;
    float xs = xsqw[row];
    float bd = 3.0e38f; int bk = 0x7fffffff;
    for (int cidx = 0; cidx < nc; ++cidx) {
        int k = cand[cidx] & (KK - 1);
        const float* er = E + (size_t)k * DD;
        float q1 = 0.f, q2 = 0.f;
        for (int d = 0; d < 384; ++d)   q1 = fmaf(xr[d], er[d], q1);
        for (int d = 384; d < 512; ++d) q2 = fmaf(xr[d], er[d], q2);
        float dot = __fadd_rn(q1, q2);
        float t1  = __fadd_rn(xs, esqw[k]);
        float dnp = __fsub_rn(t1, __fmul_rn(2.0f, dot));
        if (dnp < bd || (dnp == bd && k < bk)) { bd = dnp; bk = k; }
    }
    const float* er = E + (size_t)bk * DD;
    double ls = 0.0;
    for (int d = 0; d < DD; ++d) {
        double df = (double)xr[d] - (double)er[d];
        ls = fma(df, df, ls);
    }
    idxbuf[row] = bk;
    out[IDX_OFF + row] = (float)bk;
    atomicAdd(&hist[bk], 1);
    lred[threadIdx.x] = ls;
    __syncthreads();
    for (int t = 128; t > 0; t >>= 1) {
        if (threadIdx.x < t) lred[threadIdx.x] += lred[threadIdx.x + t];
        __syncthreads();
    }
    if (threadIdx.x == 0) atomicAdd(loss_acc, lred[0]);
}

// one block per row: quantized gather (coalesced) + one-hot row
__global__ __launch_bounds__(256) void encq_kernel(const int* __restrict__ idxbuf,
                                                   const float* __restrict__ E,
                                                   float* __restrict__ out) {
    int row = blockIdx.x;
    int idx = idxbuf[row];
    ((float2*)out)[(size_t)row * 256 + threadIdx.x] =
        ((const float2*)E)[(size_t)idx * 256 + threadIdx.x];
    float2* erow = (float2*)(out + ENC_OFF) + (size_t)row * (KK / 2);
    int half = idx >> 1;
    float2 one;
    if (idx & 1) { one.x = 0.f; one.y = 1.f; } else { one.x = 1.f; one.y = 0.f; }
    float2 z; z.x = 0.f; z.y = 0.f;
    for (int c = threadIdx.x; c < KK / 2; c += 256)
        erow[c] = (c == half) ? one : z;
}

__global__ __launch_bounds__(256) void fin_kernel(const int* __restrict__ hist,
                                                  const double* __restrict__ loss_acc,
                                                  float* __restrict__ out) {
    __shared__ double red[256];
    int tid = threadIdx.x;
    double s = 0.0;
    for (int k = tid; k < KK; k += 256) {
        double p = (double)hist[k] * (1.0 / 32768.0);
        s += p * log(p + 1e-10);
    }
    red[tid] = s;
    __syncthreads();
    for (int t = 128; t > 0; t >>= 1) {
        if (tid < t) red[tid] += red[tid + t];
        __syncthreads();
    }
    if (tid == 0) {
        double perp = exp(-red[0]);
        double L = loss_acc[0] * (1.0 / ((double)BB * (double)DD));
        out[LOSS_OFF] = (float)(1.25 * L);
        out[PERP_OFF] = (float)perp;
    }
}

extern "C" void kernel_launch(void* const* d_in, const int* in_sizes, int n_in,
                              void* d_out, int out_size, void* d_ws, size_t ws_size,
                              hipStream_t stream) {
    const float* X; const float* E;
    if (in_sizes[0] == BB * DD) { X = (const float*)d_in[0]; E = (const float*)d_in[1]; }
    else                        { X = (const float*)d_in[1]; E = (const float*)d_in[0]; }
    float* out = (float*)d_out;

    float* xsq = (float*)((char*)d_ws + WSB_XSQ);
    float* esq = (float*)((char*)d_ws + WSB_ESQ);
    int* idxbuf = (int*)((char*)d_ws + WSB_IDX);
    int* hist   = (int*)((char*)d_ws + WSB_HIST);
    double* loss_acc = (double*)((char*)d_ws + WSB_LOSS);
    unsigned short* Ebf2 = (unsigned short*)((char*)d_ws + WSB_EBF2);
    unsigned short* Xbf  = (unsigned short*)((char*)d_ws + WSB_XBF);
    uint2* partials = (uint2*)((char*)d_ws + WSB_PART);

    hipLaunchKernelGGL(init_kernel, dim3(16), dim3(256), 0, stream, hist, loss_acc);
    hipLaunchKernelGGL(npsum_kernel, dim3((BB + KK) / 4), dim3(256), 0, stream,
                       X, E, xsq, esq);
    hipLaunchKernelGGL(pack_kernel, dim3(1024), dim3(256), 0, stream, E, Ebf2);
    hipLaunchKernelGGL(pack_kernel, dim3(8192), dim3(256), 0, stream, X, Xbf);
    hipLaunchKernelGGL(gemm_screen, dim3(2048), dim3(512), 131072, stream,
                       Xbf, Ebf2, esq, partials);
    hipLaunchKernelGGL(reduce_kernel, dim3(BB / 256), dim3(256), 0, stream,
                       X, E, xsq, esq, partials, idxbuf, hist, loss_acc, out);
    hipLaunchKernelGGL(encq_kernel, dim3(BB), dim3(256), 0, stream, idxbuf, E, out);
    hipLaunchKernelGGL(fin_kernel, dim3(1), dim3(256), 0, stream, hist, loss_acc, out);
}

// Round 13
// 458.373 us; speedup vs baseline: 1.0677x; 1.0677x over previous
//
#include <hip/hip_runtime.h>
#include <hip/hip_bf16.h>

// VectorQuantizer B=32768, K=4096, D=512, fp32 in/out.
// Out concat (f32): quantized_st[B*512] | indices[B] | loss | perplexity | encodings[B*4096].
// R13: m97-occupancy GEMM screen. 128^2 tile, BK=32, 32KB LDS dbuf -> 4 blocks/CU
// (cross-block overlap hides barrier drain, per m114/m97). npsum fused with
// X bf16-packing (same sq LDS content -> numpy tree bit-identical). Epilogue/
// partials/reduce/encq verbatim R11 (validated R5-R12). XCD-bijective swizzle.

typedef __attribute__((ext_vector_type(8))) short bf16x8;
typedef __attribute__((ext_vector_type(4))) float f32x4;

#define BB 32768
#define KK 4096
#define DD 512

#define IDX_OFF  (BB*DD)
#define LOSS_OFF (IDX_OFF + BB)
#define PERP_OFF (LOSS_OFF + 1)
#define ENC_OFF  (PERP_OFF + 1)

// ws byte offsets
#define WSB_XSQ  0
#define WSB_ESQ  131072
#define WSB_IDX  147456
#define WSB_HIST 278528
#define WSB_LOSS 294912
#define WSB_EBF2 294928          // 4 MB: E bf16, packed per (cb2,kt64) 32KB chunk
#define WSB_XBF  4489232         // 32 MB: X bf16, packed per (rb2,kt64) 32KB chunk
#define WSB_PART 38043664        // 16 MB: uint2 partials [64][32768]

#define MARG 2.5e-4f
#define NCAND 16

static __device__ __forceinline__ unsigned short f2bf(float f) {
    __hip_bfloat16 h = __float2bfloat16(f);
    return *reinterpret_cast<unsigned short*>(&h);
}

static __device__ __forceinline__ unsigned int packscore(float s, int col) {
    unsigned int u = __float_as_uint(s);
    u ^= (u & 0x80000000u) ? 0xFFFFFFFFu : 0x80000000u;
    return (u & 0xFFFFF000u) | (unsigned int)col;
}
static __device__ __forceinline__ float unpackscore(unsigned int p) {
    unsigned int u = p & 0xFFFFF000u;
    u = (u & 0x80000000u) ? (u ^ 0x80000000u) : ~u;
    return __uint_as_float(u);
}

static __device__ __forceinline__ void gll16(const void* g, void* l) {
    __builtin_amdgcn_global_load_lds(
        (const __attribute__((address_space(1))) unsigned int*)g,
        (__attribute__((address_space(3))) unsigned int*)l, 16, 0, 0);
}

__global__ __launch_bounds__(256) void init_kernel(int* __restrict__ hist,
                                                   double* __restrict__ loss_acc) {
    int i = blockIdx.x * 256 + threadIdx.x;
    if (i < KK) hist[i] = 0;
    if (i == 0) *loss_acc = 0.0;
}

// numpy-emulated row sum-of-squares (pairwise-128 + AVX512 lane fold; tree math
// bit-identical to R5-R12) FUSED with X bf16 fragment-packing.
// Thread (w,lane) loads rows[blk*4+w], k = lane*8 .. lane*8+7 (contiguous).
__global__ __launch_bounds__(256) void npsum_pack_kernel(const float* __restrict__ X,
                                                         const float* __restrict__ E,
                                                         float* __restrict__ xsq,
                                                         float* __restrict__ esq,
                                                         unsigned short* __restrict__ Xbf) {
    __shared__ float sq[4][512];
    __shared__ float ub[4][64];
    __shared__ float bb[4][4];
    int w = threadIdx.x >> 6, lane = threadIdx.x & 63;
    int row = blockIdx.x * 4 + w;
    const float* src; float* dst;
    bool isx = (row < BB);
    if (isx) { src = X + (size_t)row * DD;        dst = xsq + row; }
    else     { src = E + (size_t)(row - BB) * DD; dst = esq + (row - BB); }
    const float4* s4 = (const float4*)(src + lane * 8);
    float4 a = s4[0], b = s4[1];
    sq[w][lane * 8 + 0] = __fmul_rn(a.x, a.x);
    sq[w][lane * 8 + 1] = __fmul_rn(a.y, a.y);
    sq[w][lane * 8 + 2] = __fmul_rn(a.z, a.z);
    sq[w][lane * 8 + 3] = __fmul_rn(a.w, a.w);
    sq[w][lane * 8 + 4] = __fmul_rn(b.x, b.x);
    sq[w][lane * 8 + 5] = __fmul_rn(b.y, b.y);
    sq[w][lane * 8 + 6] = __fmul_rn(b.z, b.z);
    sq[w][lane * 8 + 7] = __fmul_rn(b.w, b.w);
    if (isx) {   // emit Xbf fragment-packed unit for [row][lane*8 ..+7]
        int kt64 = lane >> 3, ks = (lane >> 2) & 1, oct = lane & 3;
        int rf = (row >> 4) & 15;
        size_t unit = ((size_t)((row >> 8) * 8 + kt64)) * 2048
                    + (size_t)((rf * 2 + ks) * 64 + oct * 16 + (row & 15));
        union { bf16x8 v; unsigned short us[8]; } pk;
        pk.us[0] = f2bf(a.x); pk.us[1] = f2bf(a.y); pk.us[2] = f2bf(a.z); pk.us[3] = f2bf(a.w);
        pk.us[4] = f2bf(b.x); pk.us[5] = f2bf(b.y); pk.us[6] = f2bf(b.z); pk.us[7] = f2bf(b.w);
        *(bf16x8*)(Xbf + unit * 8) = pk.v;
    }
    __syncthreads();
    {
        int b2 = lane >> 4, l = lane & 15;
        const float* s = &sq[w][b2 * 128];
        float t = __fadd_rn(
            __fadd_rn(__fadd_rn(s[l], s[16 + l]), __fadd_rn(s[32 + l], s[48 + l])),
            __fadd_rn(__fadd_rn(s[64 + l], s[80 + l]), __fadd_rn(s[96 + l], s[112 + l])));
        ub[w][lane] = t;
    }
    __syncthreads();
    if (lane < 4) {
        const float* u = &ub[w][lane * 16];
        float T3[8], T6[4];
        #pragma unroll
        for (int i = 0; i < 8; ++i) T3[i] = __fadd_rn(u[i], u[i + 8]);
        #pragma unroll
        for (int i = 0; i < 4; ++i) T6[i] = __fadd_rn(T3[i], T3[i + 4]);
        bb[w][lane] = __fadd_rn(__fadd_rn(T6[0], T6[2]), __fadd_rn(T6[1], T6[3]));
    }
    __syncthreads();
    if (lane == 0)
        *dst = __fadd_rn(__fadd_rn(bb[w][0], bb[w][1]), __fadd_rn(bb[w][2], bb[w][3]));
}

// E fp32 -> bf16 packed 32KB chunks (256 rows x 64 k), as R12 pack layout.
__global__ __launch_bounds__(256) void packE_kernel(const float* __restrict__ src,
                                                    unsigned short* __restrict__ dst) {
    int t = blockIdx.x * 256 + threadIdx.x;
    int chunk = t >> 11, u = t & 2047;
    int rb2 = chunk >> 3, kt = chunk & 7;
    int rf = u >> 7, ks = (u >> 6) & 1, lane = u & 63;
    int row = rb2 * 256 + rf * 16 + (lane & 15);
    int k   = kt * 64 + ks * 32 + (lane >> 4) * 8;
    const float4* s = (const float4*)(src + (size_t)row * DD + k);
    float4 a = s[0], b = s[1];
    union { bf16x8 v; unsigned short us[8]; } pk;
    pk.us[0] = f2bf(a.x); pk.us[1] = f2bf(a.y); pk.us[2] = f2bf(a.z); pk.us[3] = f2bf(a.w);
    pk.us[4] = f2bf(b.x); pk.us[5] = f2bf(b.y); pk.us[6] = f2bf(b.z); pk.us[7] = f2bf(b.w);
    *(bf16x8*)(dst + (size_t)t * 8) = pk.v;
}

// GEMM screen: grid 8192 = 256 rb x 32 cb (XCD-swizzled), 256 thr, 4 waves 2Mx2N.
// BK=32, LDS 32KB: A buffers [0,8K)+[8K,16K), B buffers [16K,24K)+[24K,32K).
__global__ __launch_bounds__(256, 4) void gemm_screen(
    const unsigned short* __restrict__ Xbf, const unsigned short* __restrict__ Ebf2,
    const float* __restrict__ esqw, uint2* __restrict__ partials)
{
    __shared__ __align__(16) char pool[32768];

    const int tid = threadIdx.x;
    const int w = tid >> 6, lane = tid & 63;
    const int c = lane & 15, g = lane >> 4;
    const int bid = blockIdx.x;
    const int orig = (bid & 7) * 1024 + (bid >> 3);   // bijective: 8192 % 8 == 0
    const int rb = orig >> 5, cb = orig & 31;
    const int row0 = rb * 128, col0 = cb * 128;
    const int mw = w >> 1, nw = w & 1;

    const int hA = rb & 1, hB = cb & 1;               // 128-row half of 256-row chunk
    const char* Xc = (const char*)Xbf  + (size_t)(rb >> 1) * 8 * 32768;
    const char* Ec = (const char*)Ebf2 + (size_t)(cb >> 1) * 8 * 32768;

    f32x4 acc[4][4];
    #pragma unroll
    for (int i = 0; i < 4; ++i)
        #pragma unroll
        for (int j = 0; j < 4; ++j) acc[i][j] = (f32x4){0.f, 0.f, 0.f, 0.f};

    // stage 8KB = 128 rows x 32 k of chunk(kt64), sub-slice (h, ks=kt&1).
    // unit rf2 = h*8 + it*4 + w  (wave-uniform per call), lanes fill 1KB.
    #define STAGE(srcc_, h_, kt_, dstoff_) { \
        const char* sb_ = (srcc_) + (size_t)((kt_) >> 1) * 32768; \
        const int ks_ = (kt_) & 1; \
        _Pragma("unroll") for (int it_ = 0; it_ < 2; ++it_) { \
            const char* s_ = sb_ + (size_t)((((h_) * 8 + it_ * 4 + w) * 2 + ks_) * 64 + lane) * 16; \
            char* d_ = pool + (dstoff_) + (it_ * 4 + w) * 1024; \
            gll16(s_, d_); } }

    STAGE(Xc, hA, 0, 0); STAGE(Ec, hB, 0, 16384);
    __syncthreads();
    int buf = 0;
    for (int kt = 0; kt < 16; ++kt) {
        if (kt < 15) {
            STAGE(Xc, hA, kt + 1, (buf ^ 1) * 8192);
            STAGE(Ec, hB, kt + 1, 16384 + (buf ^ 1) * 8192);
        }
        const char* Ap = pool + buf * 8192;
        const char* Bp = pool + 16384 + buf * 8192;
        bf16x8 af[4], bfr[4];
        #pragma unroll
        for (int i = 0; i < 4; ++i) {
            af[i]  = *(const bf16x8*)(Ap + (((mw * 4 + i) * 64) + lane) * 16);
            bfr[i] = *(const bf16x8*)(Bp + (((nw * 4 + i) * 64) + lane) * 16);
        }
        #pragma unroll
        for (int mf = 0; mf < 4; ++mf)
            #pragma unroll
            for (int nf = 0; nf < 4; ++nf)
                acc[mf][nf] = __builtin_amdgcn_mfma_f32_16x16x32_bf16(af[mf], bfr[nf], acc[mf][nf], 0, 0, 0);
        __syncthreads();
        buf ^= 1;
    }

    // epilogue: scores -> per-lane top2-of-4nf -> LDS -> per-(row,nw) top2 -> partials
    uint2* P = (uint2*)pool;   // [2][128][16] = 32 KB (aliases pool after last barrier)
    #pragma unroll
    for (int mf = 0; mf < 4; ++mf) {
        #pragma unroll
        for (int r = 0; r < 4; ++r) {
            unsigned int q1 = 0xFFFFFFFFu, q2 = 0xFFFFFFFFu;
            int rowl = mw * 64 + mf * 16 + g * 4 + r;
            #pragma unroll
            for (int nf = 0; nf < 4; ++nf) {
                int col = col0 + nw * 64 + nf * 16 + c;
                float s = fmaf(-2.0f, acc[mf][nf][r], esqw[col]);
                unsigned int q = packscore(s, col);
                if (q < q1) { q2 = q1; q1 = q; } else if (q < q2) q2 = q;
            }
            P[(nw * 128 + rowl) * 16 + c] = make_uint2(q1, q2);
        }
    }
    __syncthreads();
    if (tid < 128) {
        int row = tid;
        #pragma unroll
        for (int n2 = 0; n2 < 2; ++n2) {
            unsigned int m1 = 0xFFFFFFFFu, m2 = 0xFFFFFFFFu;
            #pragma unroll 4
            for (int cc = 0; cc < 16; ++cc) {
                uint2 e = P[(n2 * 128 + row) * 16 + cc];
                if (e.x < m1) { m2 = m1; m1 = e.x; } else if (e.x < m2) m2 = e.x;
                if (e.y < m1) { m2 = m1; m1 = e.y; } else if (e.y < m2) m2 = e.y;
            }
            partials[(size_t)(cb * 2 + n2) * BB + row0 + row] = make_uint2(m1, m2);
        }
    }
    #undef STAGE
}

// merge partials -> candidates -> numpy-fp32 rescore -> idx/hist/loss (verbatim R11/R12)
__global__ __launch_bounds__(256) void reduce_kernel(
    const float* __restrict__ X, const float* __restrict__ E,
    const float* __restrict__ xsqw, const float* __restrict__ esqw,
    const uint2* __restrict__ partials, int* __restrict__ idxbuf,
    int* __restrict__ hist, double* __restrict__ loss_acc,
    float* __restrict__ out)
{
    __shared__ double lred[256];
    const int row = blockIdx.x * 256 + threadIdx.x;
    unsigned int m = 0xFFFFFFFFu;
    for (int e = 0; e < 64; ++e) m = min(m, partials[(size_t)e * BB + row].x);
    float lim = unpackscore(m) + MARG;
    int cand[NCAND]; int nc = 0;
    for (int e = 0; e < 64; ++e) {
        uint2 p = partials[(size_t)e * BB + row];
        if (unpackscore(p.x) <= lim && nc < NCAND) cand[nc++] = (int)(p.x & 0xFFFu);
        if (unpackscore(p.y) <= lim && nc < NCAND) cand[nc++] = (int)(p.y & 0xFFFu);
    }
    const float* xr = X + (size_t)row * DD;
    float xs = xsqw[row];
    float bd = 3.0e38f; int bk = 0x7fffffff;
    for (int cidx = 0; cidx < nc; ++cidx) {
        int k = cand[cidx] & (KK - 1);
        const float* er = E + (size_t)k * DD;
        float q1 = 0.f, q2 = 0.f;
        for (int d = 0; d < 384; ++d)   q1 = fmaf(xr[d], er[d], q1);
        for (int d = 384; d < 512; ++d) q2 = fmaf(xr[d], er[d], q2);
        float dot = __fadd_rn(q1, q2);
        float t1  = __fadd_rn(xs, esqw[k]);
        float dnp = __fsub_rn(t1, __fmul_rn(2.0f, dot));
        if (dnp < bd || (dnp == bd && k < bk)) { bd = dnp; bk = k; }
    }
    const float* er = E + (size_t)bk * DD;
    double ls = 0.0;
    for (int d = 0; d < DD; ++d) {
        double df = (double)xr[d] - (double)er[d];
        ls = fma(df, df, ls);
    }
    idxbuf[row] = bk;
    out[IDX_OFF + row] = (float)bk;
    atomicAdd(&hist[bk], 1);
    lred[threadIdx.x] = ls;
    __syncthreads();
    for (int t = 128; t > 0; t >>= 1) {
        if (threadIdx.x < t) lred[threadIdx.x] += lred[threadIdx.x + t];
        __syncthreads();
    }
    if (threadIdx.x == 0) atomicAdd(loss_acc, lred[0]);
}

// one block per row: quantized gather (coalesced) + one-hot row
__global__ __launch_bounds__(256) void encq_kernel(const int* __restrict__ idxbuf,
                                                   const float* __restrict__ E,
                                                   float* __restrict__ out) {
    int row = blockIdx.x;
    int idx = idxbuf[row];
    ((float2*)out)[(size_t)row * 256 + threadIdx.x] =
        ((const float2*)E)[(size_t)idx * 256 + threadIdx.x];
    float2* erow = (float2*)(out + ENC_OFF) + (size_t)row * (KK / 2);
    int half = idx >> 1;
    float2 one;
    if (idx & 1) { one.x = 0.f; one.y = 1.f; } else { one.x = 1.f; one.y = 0.f; }
    float2 z; z.x = 0.f; z.y = 0.f;
    for (int c = threadIdx.x; c < KK / 2; c += 256)
        erow[c] = (c == half) ? one : z;
}

__global__ __launch_bounds__(256) void fin_kernel(const int* __restrict__ hist,
                                                  const double* __restrict__ loss_acc,
                                                  float* __restrict__ out) {
    __shared__ double red[256];
    int tid = threadIdx.x;
    double s = 0.0;
    for (int k = tid; k < KK; k += 256) {
        double p = (double)hist[k] * (1.0 / 32768.0);
        s += p * log(p + 1e-10);
    }
    red[tid] = s;
    __syncthreads();
    for (int t = 128; t > 0; t >>= 1) {
        if (tid < t) red[tid] += red[tid + t];
        __syncthreads();
    }
    if (tid == 0) {
        double perp = exp(-red[0]);
        double L = loss_acc[0] * (1.0 / ((double)BB * (double)DD));
        out[LOSS_OFF] = (float)(1.25 * L);
        out[PERP_OFF] = (float)perp;
    }
}

extern "C" void kernel_launch(void* const* d_in, const int* in_sizes, int n_in,
                              void* d_out, int out_size, void* d_ws, size_t ws_size,
                              hipStream_t stream) {
    const float* X; const float* E;
    if (in_sizes[0] == BB * DD) { X = (const float*)d_in[0]; E = (const float*)d_in[1]; }
    else                        { X = (const float*)d_in[1]; E = (const float*)d_in[0]; }
    float* out = (float*)d_out;

    float* xsq = (float*)((char*)d_ws + WSB_XSQ);
    float* esq = (float*)((char*)d_ws + WSB_ESQ);
    int* idxbuf = (int*)((char*)d_ws + WSB_IDX);
    int* hist   = (int*)((char*)d_ws + WSB_HIST);
    double* loss_acc = (double*)((char*)d_ws + WSB_LOSS);
    unsigned short* Ebf2 = (unsigned short*)((char*)d_ws + WSB_EBF2);
    unsigned short* Xbf  = (unsigned short*)((char*)d_ws + WSB_XBF);
    uint2* partials = (uint2*)((char*)d_ws + WSB_PART);

    hipLaunchKernelGGL(init_kernel, dim3(16), dim3(256), 0, stream, hist, loss_acc);
    hipLaunchKernelGGL(npsum_pack_kernel, dim3((BB + KK) / 4), dim3(256), 0, stream,
                       X, E, xsq, esq, Xbf);
    hipLaunchKernelGGL(packE_kernel, dim3(1024), dim3(256), 0, stream, E, Ebf2);
    hipLaunchKernelGGL(gemm_screen, dim3(8192), dim3(256), 0, stream,
                       Xbf, Ebf2, esq, partials);
    hipLaunchKernelGGL(reduce_kernel, dim3(BB / 256), dim3(256), 0, stream,
                       X, E, xsq, esq, partials, idxbuf, hist, loss_acc, out);
    hipLaunchKernelGGL(encq_kernel, dim3(BB), dim3(256), 0, stream, idxbuf, E, out);
    hipLaunchKernelGGL(fin_kernel, dim3(1), dim3(256), 0, stream, hist, loss_acc, out);
}